// Round 4
// baseline (148.791 us; speedup 1.0000x reference)
//
#include <hip/hip_runtime.h>
#include <math.h>

#define LMAX  32768
#define WWIN  1024
#define KFIR  128
#define WOUT  1024               // outputs per wave (four 256-output MFMA chunks)
#define TO    1024               // outputs per block (1 window x 4 note-groups)
#define CPAD  1232               // shift-copy length; 2464B stride (16B mult, ==32 mod 128 -> balanced banks)
#define SYNTH 1152               // synthesized samples per visit (127 history + 1024 + 1)
#define ZPS   1148               // zero-pad start (SYNTH-4 covers all shifted copies)
#define NMAX  1024               // max notes
#define SLOT  128                // per-tile note-list capacity (K_max ~ 31 for this input dist)

typedef _Float16 v8h __attribute__((ext_vector_type(8)));
typedef _Float16 v4h __attribute__((ext_vector_type(4)));
typedef float    v4f __attribute__((ext_vector_type(4)));

__device__ __forceinline__ float fast_tanh(float x) {
    float e = __builtin_amdgcn_exp2f(x * 2.8853900817779268f);  // 2*log2(e)
    return fmaf(-2.0f, __builtin_amdgcn_rcpf(e + 1.0f), 1.0f);
}

// ---------------- setup kernel A: per-note params + tile binning ----------------
// r19: R0/R2/R3 all pinned at 73us across 3 structural changes -> the invariant
// cost is the PER-BLOCK prologue (1292 blocks x {full 1024-note scan, weight
// staging, ~14 redundant amplitude-MLP evals on 96/256 lanes}) plus the
// K-oblivious dispatch tail.  This kernel computes each note's MLP exactly
// once (1024 evals, all lanes busy) and bins notes into per-tile lists in ws.
__global__ __launch_bounds__(256) void setup_notes_k(
    const float* __restrict__ freq_g, const float* __restrict__ velo_g,
    const float* __restrict__ w1,  const float* __restrict__ b1,
    const float* __restrict__ w2,  const float* __restrict__ b2,
    const float* __restrict__ ws1, const float* __restrict__ bs1,
    const float* __restrict__ ws2, const float* __restrict__ bs2,
    const int* __restrict__ starts, const int* __restrict__ lengths,
    float* __restrict__ npar, int* __restrict__ counts,
    unsigned short* __restrict__ lists,
    int Dn, int N, int n_tiles)
{
    __shared__ float s_w1[32], s_b1[32], s_w2[64], s_b2[2];
    __shared__ float s_ws1[256], s_bs1[64], s_ws2[512], s_bs2[8];
    const int tid = threadIdx.x;
    if (tid < 32) { s_w1[tid] = w1[tid]; s_b1[tid] = b1[tid]; }
    if (tid < 64) { s_w2[tid] = w2[tid]; s_bs1[tid] = bs1[tid]; }
    if (tid < 2)  s_b2[tid] = b2[tid];
    if (tid < 8)  s_bs2[tid] = bs2[tid];
    s_ws1[tid] = ws1[tid];
    s_ws2[tid] = ws2[tid];  s_ws2[tid + 256] = ws2[tid + 256];
    __syncthreads();

    const int j = blockIdx.x * 256 + tid;
    if (j >= N) return;

    int st  = starts[j];
    int len = lengths[j];
    int ol  = min(st + len, Dn) - st;
    ol = max(0, min(ol, LMAX));
    float v = velo_g[j] * (1.0f / 127.0f);
    float f = freq_g[j];
    float nt = (float)st / (float)Dn;
    float lat0 = s_b2[0], lat1 = s_b2[1];
    #pragma unroll
    for (int jj = 0; jj < 32; ++jj) {
        float h = fmaxf(fmaf(nt, s_w1[jj], s_b1[jj]), 0.0f);
        lat0 = fmaf(h, s_w2[jj * 2 + 0], lat0);
        lat1 = fmaf(h, s_w2[jj * 2 + 1], lat1);
    }
    float acc[8];
    #pragma unroll
    for (int h = 0; h < 8; ++h) acc[h] = s_bs2[h];
    #pragma unroll
    for (int jj = 0; jj < 64; ++jj) {
        float a = s_bs1[jj];
        a = fmaf(f,    s_ws1[0 * 64 + jj], a);
        a = fmaf(v,    s_ws1[1 * 64 + jj], a);
        a = fmaf(lat0, s_ws1[2 * 64 + jj], a);
        a = fmaf(lat1, s_ws1[3 * 64 + jj], a);
        a = fmaxf(a, 0.0f);
        #pragma unroll
        for (int h = 0; h < 8; ++h)
            acc[h] = fmaf(a, s_ws2[jj * 8 + h], acc[h]);
    }
    float* p = npar + (size_t)j * 12;
    p[0] = __int_as_float(st);
    p[1] = __int_as_float(ol);
    p[2] = f;
    p[3] = 0.0f;
    #pragma unroll
    for (int h = 0; h < 8; ++h) {
        float a = acc[h];
        float sp = fmaxf(a, 0.0f) + log1pf(expf(-fabsf(a)));
        p[4 + h] = sp * v;                 // velocity folded in
    }

    if (ol > 0) {
        int t0 = st >> 10;
        int t1 = min((st + ol - 1) >> 10, n_tiles - 1);
        for (int t = t0; t <= t1; ++t) {
            int pos = atomicAdd(&counts[t], 1);
            if (pos < SLOT) lists[(size_t)t * SLOT + pos] = (unsigned short)j;
        }
    }
}

// ---------------- setup kernel B: LPT tile order (bucket sort by K desc) ------
__global__ __launch_bounds__(1024) void sort_tiles_k(
    const int* __restrict__ counts, int* __restrict__ order, int n_tiles)
{
    __shared__ int hist[SLOT + 2];
    __shared__ int bstart[SLOT + 2];
    const int tid = threadIdx.x;
    if (tid < SLOT + 2) hist[tid] = 0;
    __syncthreads();
    for (int t = tid; t < n_tiles; t += 1024) {
        int k = min(counts[t], SLOT + 1);
        atomicAdd(&hist[k], 1);
    }
    __syncthreads();
    if (tid == 0) {
        int run = 0;
        for (int k = SLOT + 1; k >= 0; --k) { bstart[k] = run; run += hist[k]; }
    }
    __syncthreads();
    for (int t = tid; t < n_tiles; t += 1024) {
        int k = min(counts[t], SLOT + 1);
        int p = atomicAdd(&bstart[k], 1);
        order[p] = t;
    }
}

// ---------------- main fused kernel ----------------
// Synth/MFMA core identical to R3 (verified); prologue reduced to
// {FIR stage + <=K x 48B param copy}; heavy tiles dispatched first.
__global__ __launch_bounds__(256, 3) void synth_fused_k(
    const float* __restrict__ fir,
    const float* __restrict__ npar,
    const int* __restrict__ counts,
    const unsigned short* __restrict__ lists,
    const int* __restrict__ order,
    float* __restrict__ out, int Dn)
{
    __shared__ __align__(16) _Float16 segc[4][4][CPAD];   // 38.5 KB (per-wave scratch)
    __shared__ float fir_s[KFIR];
    __shared__ int   stl[SLOT], oll[SLOT];
    __shared__ float fl[SLOT];
    __shared__ __align__(16) float ampsl[SLOT][8];

    const int tid  = threadIdx.x;
    const int wid  = tid >> 6;          // 0..3
    const int lane = tid & 63;
    const int m    = lane & 15;
    const int quad = lane >> 4;
    const int grp  = wid;               // note group (0..3); all waves share the window
    const int tile = order[blockIdx.x];
    const int o0   = tile * TO;
    const int ow   = o0;                // wave's first output == tile base

    const int K = min(counts[tile], SLOT);

    // ---- stage FIR taps + precomputed note params ----
    if (tid < KFIR) fir_s[tid] = fir[tid];
    if (tid < K) {
        const int nid = (int)lists[(size_t)tile * SLOT + tid];
        const float4* pp = (const float4*)(npar + (size_t)nid * 12);
        float4 a = pp[0], b = pp[1], c = pp[2];
        stl[tid] = __float_as_int(a.x);
        oll[tid] = __float_as_int(a.y);
        fl[tid]  = a.z;
        *(float4*)&ampsl[tid][0] = b;
        *(float4*)&ampsl[tid][4] = c;
    }
    __syncthreads();

    // ---- A fragments + zero-pad (wave-local) ----
    v8h afrag[12];
    #pragma unroll
    for (int t = 0; t < 12; ++t) {
        v8h af;
        #pragma unroll
        for (int j = 0; j < 8; ++j) {
            int idx = 32 * t + 8 * quad + j - 16 * m;
            float fv = (idx >= 0 && idx < KFIR) ? fir_s[idx] : 0.0f;
            af[j] = (_Float16)fv;
        }
        afrag[t] = af;
    }
    // zero-pad the tail of every shifted copy: [ZPS, CPAD) x 4 copies
    for (int z = lane; z < 4 * (CPAD - ZPS); z += 64) {
        int S = z / (CPAD - ZPS), off = z % (CPAD - ZPS);
        segc[wid][S][ZPS + off] = (_Float16)0.0f;
    }

    // per-lane B read base: copy c = m&3, in-copy half index (m&~3)+8*quad (8B aligned)
    const _Float16* __restrict__ bbase = &segc[wid][m & 3][(m & ~3) + 8 * quad];

    float accv[16];
    #pragma unroll
    for (int r = 0; r < 16; ++r) accv[r] = 0.0f;

    const double inv2pi = 0.15915494309189535;

    // ---- prefetch this group's first note (register pipeline) ----
    int stN = 0, olN = 0; float fN = 0.f;
    float4 amN0 = {}, amN1 = {};
    if (grp < K) {
        stN = stl[grp]; olN = oll[grp]; fN = fl[grp];
        amN0 = *(const float4*)&ampsl[grp][0];
        amN1 = *(const float4*)&ampsl[grp][4];
    }

    for (int kk = grp; kk < K; kk += 4) {
        const int st = stN, ol = olN;
        const float f = fN;
        const float4 am0 = amN0, am1 = amN1;
        if (kk + 4 < K) {                 // issue next note's LDS loads now
            stN = stl[kk + 4]; olN = oll[kk + 4]; fN = fl[kk + 4];
            amN0 = *(const float4*)&ampsl[kk + 4][0];
            amN1 = *(const float4*)&ampsl[kk + 4][4];
        }

        const int base = ow - st;         // note-local index of wave's first output
        if (base >= ol || base + WOUT <= 0) continue;   // wave-uniform skip

        const float A0 = am0.x, A1 = am0.y, A2 = am0.z, A3 = am0.w;
        const float A4 = am1.x, A5 = am1.y, A6 = am1.z, A7 = am1.w;
        const double fd = (double)f;

        const int tseed = base - 127 + lane;
        double rev0 = fd * (double)tseed * inv2pi;
        float r0 = (float)(rev0 - floor(rev0));
        float s = __builtin_amdgcn_sinf(r0);
        float cc = __builtin_amdgcn_cosf(r0);
        double d64 = fd * 64.0 * inv2pi;
        float r64 = (float)(d64 - floor(d64));
        const float sd = __builtin_amdgcn_sinf(r64);
        const float cd = __builtin_amdgcn_cosf(r64);
        const int wbase = ol - WWIN;

        const bool interior = (base >= 127) && (base + WOUT + 1 <= wbase);

        if (interior) {
            #pragma unroll
            for (int i = 0; i < SYNTH / 64; ++i) {
                float tc = cc + cc;
                float sA = s;
                float sum = A0 * sA;
                float sB = tc * sA;              sum = fmaf(A1, sB, sum);
                float sC = fmaf(tc, sB, -sA);    sum = fmaf(A2, sC, sum);
                float sD = fmaf(tc, sC, -sB);    sum = fmaf(A3, sD, sum);
                float sE = fmaf(tc, sD, -sC);    sum = fmaf(A4, sE, sum);
                float sF = fmaf(tc, sE, -sD);    sum = fmaf(A5, sF, sum);
                float sG = fmaf(tc, sF, -sE);    sum = fmaf(A6, sG, sum);
                float sH = fmaf(tc, sG, -sF);    sum = fmaf(A7, sH, sum);
                _Float16 h = (_Float16)sum;
                const int x = lane + 64 * i;
                if (i == 0) {
                    #pragma unroll
                    for (int S = 0; S < 4; ++S)
                        if (x >= S) segc[wid][S][x - S] = h;
                } else {
                    #pragma unroll
                    for (int S = 0; S < 4; ++S)
                        segc[wid][S][x - S] = h;
                }
                float ns = fmaf(s, cd, cc * sd);
                float nc = fmaf(cc, cd, -(s * sd));
                s = ns; cc = nc;
            }
        } else {
            #pragma unroll
            for (int i = 0; i < SYNTH / 64; ++i) {
                int t = tseed + 64 * i;
                float val = 0.0f;
                if (t >= 0 && t < ol) {
                    float tc = cc + cc;
                    float sA = s;
                    float sum = A0 * sA;
                    float sB = tc * sA;              sum = fmaf(A1, sB, sum);
                    float sC = fmaf(tc, sB, -sA);    sum = fmaf(A2, sC, sum);
                    float sD = fmaf(tc, sC, -sB);    sum = fmaf(A3, sD, sum);
                    float sE = fmaf(tc, sD, -sC);    sum = fmaf(A4, sE, sum);
                    float sF = fmaf(tc, sE, -sD);    sum = fmaf(A5, sF, sum);
                    float sG = fmaf(tc, sF, -sE);    sum = fmaf(A6, sG, sum);
                    float sH = fmaf(tc, sG, -sF);    sum = fmaf(A7, sH, sum);
                    int wpos = t - wbase;
                    float factor = 1.0f;
                    if (wpos >= 0)
                        factor = 0.5f - 0.5f * __builtin_amdgcn_cosf((float)wpos * (1.0f / WWIN));
                    val = sum * factor;
                }
                _Float16 h = (_Float16)val;
                const int x = lane + 64 * i;
                if (i == 0) {
                    #pragma unroll
                    for (int S = 0; S < 4; ++S)
                        if (x >= S) segc[wid][S][x - S] = h;
                } else {
                    #pragma unroll
                    for (int S = 0; S < 4; ++S)
                        segc[wid][S][x - S] = h;
                }
                float ns = fmaf(s, cd, cc * sd);
                float nc = fmaf(cc, cd, -(s * sd));
                s = ns; cc = nc;
            }
        }

        // ---- FIR as 48x MFMA over 4 output chunks (2 passes of 2 chunks) ----
        #pragma unroll
        for (int p = 0; p < 2; ++p) {
            const int co = 512 * p;       // sample offset of this pass
            v4f CA0 = {0.f, 0.f, 0.f, 0.f};
            v4f CA1 = {0.f, 0.f, 0.f, 0.f};
            v4f CB0 = {0.f, 0.f, 0.f, 0.f};
            v4f CB1 = {0.f, 0.f, 0.f, 0.f};
            #pragma unroll
            for (int t = 0; t < 6; ++t) {
                v4h lo = *(const v4h*)(bbase + co + 32 * t);
                v4h hi = *(const v4h*)(bbase + co + 32 * t + 4);
                v8h bf = __builtin_shufflevector(lo, hi, 0, 1, 2, 3, 4, 5, 6, 7);
                CA0 = __builtin_amdgcn_mfma_f32_16x16x32_f16(afrag[t], bf, CA0, 0, 0, 0);
                v4h lo2 = *(const v4h*)(bbase + co + 256 + 32 * t);
                v4h hi2 = *(const v4h*)(bbase + co + 256 + 32 * t + 4);
                v8h bf2 = __builtin_shufflevector(lo2, hi2, 0, 1, 2, 3, 4, 5, 6, 7);
                CB0 = __builtin_amdgcn_mfma_f32_16x16x32_f16(afrag[t], bf2, CB0, 0, 0, 0);
            }
            #pragma unroll
            for (int t = 6; t < 12; ++t) {
                v4h lo = *(const v4h*)(bbase + co + 32 * t);
                v4h hi = *(const v4h*)(bbase + co + 32 * t + 4);
                v8h bf = __builtin_shufflevector(lo, hi, 0, 1, 2, 3, 4, 5, 6, 7);
                CA1 = __builtin_amdgcn_mfma_f32_16x16x32_f16(afrag[t], bf, CA1, 0, 0, 0);
                v4h lo2 = *(const v4h*)(bbase + co + 256 + 32 * t);
                v4h hi2 = *(const v4h*)(bbase + co + 256 + 32 * t + 4);
                v8h bf2 = __builtin_shufflevector(lo2, hi2, 0, 1, 2, 3, 4, 5, 6, 7);
                CB1 = __builtin_amdgcn_mfma_f32_16x16x32_f16(afrag[t], bf2, CB1, 0, 0, 0);
            }

            // ---- tanh + masked accumulate ----
            const int tb = base + co + 64 * quad + m;
            float y;
            y = CA0[0] + CA1[0]; if (tb +   0 >= 0 && tb +   0 < ol) accv[p*8+0] += fast_tanh(y);
            y = CA0[1] + CA1[1]; if (tb +  16 >= 0 && tb +  16 < ol) accv[p*8+1] += fast_tanh(y);
            y = CA0[2] + CA1[2]; if (tb +  32 >= 0 && tb +  32 < ol) accv[p*8+2] += fast_tanh(y);
            y = CA0[3] + CA1[3]; if (tb +  48 >= 0 && tb +  48 < ol) accv[p*8+3] += fast_tanh(y);
            y = CB0[0] + CB1[0]; if (tb + 256 >= 0 && tb + 256 < ol) accv[p*8+4] += fast_tanh(y);
            y = CB0[1] + CB1[1]; if (tb + 272 >= 0 && tb + 272 < ol) accv[p*8+5] += fast_tanh(y);
            y = CB0[2] + CB1[2]; if (tb + 288 >= 0 && tb + 288 < ol) accv[p*8+6] += fast_tanh(y);
            y = CB0[3] + CB1[3]; if (tb + 304 >= 0 && tb + 304 < ol) accv[p*8+7] += fast_tanh(y);
        }
    }

    // ---- cross-group reduction (groups 1..3 -> LDS -> group 0) + stores ----
    __syncthreads();                          // all waves done with segc
    float* red = (float*)&segc[0][0][0];      // 12 KB scratch, reuse segc
    const int slot0 = 64 * quad + m;
    if (grp != 0) {
        float* rg = red + (grp - 1) * 1024;
        #pragma unroll
        for (int p = 0; p < 2; ++p) {
            #pragma unroll
            for (int r = 0; r < 8; ++r) {
                const int idx = slot0 + 512 * p + (r >> 2) * 256 + (r & 3) * 16;
                rg[idx] = accv[p * 8 + r];
            }
        }
    }
    __syncthreads();
    if (grp == 0) {
        #pragma unroll
        for (int p = 0; p < 2; ++p) {
            #pragma unroll
            for (int r = 0; r < 8; ++r) {
                const int idx = slot0 + 512 * p + (r >> 2) * 256 + (r & 3) * 16;
                float v = accv[p * 8 + r] + red[idx] + red[1024 + idx] + red[2048 + idx];
                const int ob = o0 + idx;      // C/D layout: 16-lane coalesced runs
                if (ob < Dn) out[ob] = v;
            }
        }
    }
}

// ---------------- launcher (memset + 3 dispatches) ----------------
extern "C" void kernel_launch(void* const* d_in, const int* in_sizes, int n_in,
                              void* d_out, int out_size, void* d_ws, size_t ws_size,
                              hipStream_t stream) {
    const float* freq    = (const float*)d_in[0];
    const float* velo    = (const float*)d_in[1];
    const float* w1      = (const float*)d_in[2];
    const float* b1      = (const float*)d_in[3];
    const float* w2      = (const float*)d_in[4];
    const float* b2      = (const float*)d_in[5];
    const float* ws1     = (const float*)d_in[6];
    const float* bs1     = (const float*)d_in[7];
    const float* ws2     = (const float*)d_in[8];
    const float* bs2     = (const float*)d_in[9];
    const float* fir     = (const float*)d_in[10];
    const int*   starts  = (const int*)d_in[11];
    const int*   lengths = (const int*)d_in[12];

    const int N  = in_sizes[0];
    const int Dn = out_size;
    float* out = (float*)d_out;

    const int n_tiles = (Dn + TO - 1) / TO;

    // workspace carve-up (~390 KB total): npar | counts | lists | order
    char* ws = (char*)d_ws;
    float* npar = (float*)ws;                                          // N*12 f32
    size_t off1 = ((size_t)N * 12 * sizeof(float) + 255) & ~(size_t)255;
    int* counts = (int*)(ws + off1);                                   // n_tiles i32
    size_t off2 = off1 + (((size_t)n_tiles * sizeof(int) + 255) & ~(size_t)255);
    unsigned short* lists = (unsigned short*)(ws + off2);              // n_tiles*SLOT u16
    size_t off3 = off2 + (((size_t)n_tiles * SLOT * sizeof(unsigned short) + 255) & ~(size_t)255);
    int* order = (int*)(ws + off3);                                    // n_tiles i32

    hipMemsetAsync(counts, 0, (size_t)n_tiles * sizeof(int), stream);
    setup_notes_k<<<(N + 255) / 256, 256, 0, stream>>>(
        freq, velo, w1, b1, w2, b2, ws1, bs1, ws2, bs2,
        starts, lengths, npar, counts, lists, Dn, N, n_tiles);
    sort_tiles_k<<<1, 1024, 0, stream>>>(counts, order, n_tiles);
    synth_fused_k<<<n_tiles, 256, 0, stream>>>(
        fir, npar, counts, lists, order, out, Dn);
}